// Round 3
// baseline (1119.587 us; speedup 1.0000x reference)
//
#include <hip/hip_runtime.h>
#include <hip/hip_bf16.h>

#define N 1024
#define E 128
#define NEG 0.2f
#define AST 136  // padded LDS stride (shorts) for B tile

typedef __attribute__((ext_vector_type(8))) short short8;
typedef __attribute__((ext_vector_type(4))) float float4v;

__device__ __forceinline__ short f2bf(float x){
  unsigned u = __float_as_uint(x);
  u += 0x7fffu + ((u >> 16) & 1u);   // round-to-nearest-even
  return (short)(u >> 16);
}

__device__ __forceinline__ short8 cvt2v(float4v a, float4v b){
  short8 r;
  r[0] = f2bf(a[0]); r[1] = f2bf(a[1]); r[2] = f2bf(a[2]); r[3] = f2bf(a[3]);
  r[4] = f2bf(b[0]); r[5] = f2bf(b[1]); r[6] = f2bf(b[2]); r[7] = f2bf(b[3]);
  return r;
}

// Merged prep: blocks [0,E) do prep0 (l=b); blocks [E, E+N) do prep1 (j=b-E).
__global__ void prep(const float* __restrict__ embs, const float* __restrict__ W,
                     const float* __restrict__ pc_W, const float* __restrict__ pc_b,
                     const float* __restrict__ a_W,
                     short* __restrict__ BT, float* __restrict__ w2,
                     float* __restrict__ bias, float* __restrict__ u){
  int b = blockIdx.x, t = threadIdx.x;
  __shared__ float se[E], swf[E], red[E];
  if (b < E){
    int l = b;
    BT[l*E + t] = f2bf(pc_W[(E + t)*E + l]);
    red[t] = W[l*E + t] * a_W[E + t];
    __syncthreads();
    for (int s = 64; s > 0; s >>= 1){ if (t < s) red[t] += red[t+s]; __syncthreads(); }
    if (t == 0) w2[l] = red[0];
  } else {
    int j = b - E;
    se[t] = embs[j*E + t];
    __syncthreads();
    float acc = 0.f;
    #pragma unroll 8
    for (int k = 0; k < E; k++) acc += se[k] * W[k*E + t];
    swf[t] = acc;
    __syncthreads();
    float ct = 0.f;
    #pragma unroll 8
    for (int k = 0; k < E; k++) ct += swf[k] * pc_W[k*E + t];
    bias[j*E + t] = ct + pc_b[t];
    red[t] = swf[t] * a_W[t];
    __syncthreads();
    for (int s = 64; s > 0; s >>= 1){ if (t < s) red[t] += red[t+s]; __syncthreads(); }
    if (t == 0) u[j] = red[0];
  }
}

// Fused kernel: one block per output row i. pde[i,:,:] is a CONTIGUOUS 512 KB
// stream (j-tiles of 128 rows are contiguous 64 KB blocks). Computes all 1024
// logits for row i into LDS, then mask+softmax+attn@embs+concat in-block.
// pde loads are non-temporal: single-use 512 MB stream must not evict the
// reused L2 set (bias/embs/BT/adj).
__global__ __launch_bounds__(256, 4)
void fused(const float* __restrict__ pde, const short* __restrict__ BT,
           const float* __restrict__ bias, const float* __restrict__ u,
           const float* __restrict__ w2, const float* __restrict__ a_b,
           const int* __restrict__ adj, const float* __restrict__ embs,
           float* __restrict__ out){
  __shared__ __align__(16) short sB[E*AST];   // ~34 KB
  __shared__ __align__(16) float sLog[N];     // 4 KB: logits -> exp values
  __shared__ float sW2[E];
  __shared__ float red[256];
  __shared__ float wred[4];

  const int t = threadIdx.x;
  const int i = blockIdx.x;

  // stage B (bf16, 128x128) into padded LDS
  {
    int rl = t >> 4;
    int kk = (t & 15) * 8;
    #pragma unroll
    for (int p = 0; p < 8; p++){
      int l = p*16 + rl;
      *(uint4*)(&sB[l*AST + kk]) = *(const uint4*)(&BT[l*E + kk]);
    }
  }
  if (t < 128) sW2[t] = w2[t];

  const int lane = t & 63;
  const int w = t >> 6;            // wave 0..3, j-rows [w*32, w*32+32) within tile
  const int n = lane & 15;
  const int q = lane >> 4;
  const int rw = w * 32;

  const float u_i = u[i];
  const float ab = a_b[0];

  __syncthreads();

  const float* pbase = pde + (size_t)i * N * E;

  #pragma unroll 1
  for (int jt = 0; jt < 8; jt++){
    const int j0 = jt * 128;

    // A fragments: direct global->reg from a contiguous 64 KB j-tile.
    // A[row=n][k=q*8+jj], rows are j-rows (stride E floats, contiguous).
    const float* rp0 = pbase + (size_t)(j0 + rw + n) * E + q*8;
    const float* rp1 = rp0 + 16 * E;

    short8 frag[2][4];
    #pragma unroll
    for (int ks = 0; ks < 4; ks++){
      float4v a0 = __builtin_nontemporal_load((const float4v*)(rp0 + ks*32));
      float4v a1 = __builtin_nontemporal_load((const float4v*)(rp0 + ks*32 + 4));
      float4v b0 = __builtin_nontemporal_load((const float4v*)(rp1 + ks*32));
      float4v b1 = __builtin_nontemporal_load((const float4v*)(rp1 + ks*32 + 4));
      frag[0][ks] = cvt2v(a0, a1);
      frag[1][ks] = cvt2v(b0, b1);
    }

    // bias varies with the row (j) axis: per-lane L2 loads.
    // lane needs bias[j0 + rw + q*4 + r (+16)][ct*16 + n]
    const float* bp0 = bias + (size_t)(j0 + rw + q*4) * E + n;
    const float* bp1 = bp0 + 16 * E;

    float s0[4] = {0.f, 0.f, 0.f, 0.f};   // partial logit sums, rows rw+q*4+r
    float s1[4] = {0.f, 0.f, 0.f, 0.f};   // rows +16

    #pragma unroll
    for (int ct = 0; ct < 8; ct++){
      const int l = ct*16 + n;
      short8 b[4];
      #pragma unroll
      for (int ks = 0; ks < 4; ks++)
        b[ks] = *(const short8*)(&sB[l*AST + ks*32 + q*8]);

      float4v acc0 = (float4v){0.f,0.f,0.f,0.f};
      float4v acc1 = (float4v){0.f,0.f,0.f,0.f};
      #pragma unroll
      for (int ks = 0; ks < 4; ks++){
        acc0 = __builtin_amdgcn_mfma_f32_16x16x32_bf16(frag[0][ks], b[ks], acc0, 0, 0, 0);
        acc1 = __builtin_amdgcn_mfma_f32_16x16x32_bf16(frag[1][ks], b[ks], acc1, 0, 0, 0);
      }

      const float wl = sW2[l];
      #pragma unroll
      for (int r = 0; r < 4; r++){
        float y0 = acc0[r] + bp0[r*E + ct*16];
        y0 = (y0 >= 0.f) ? y0 : NEG * y0;
        float y1 = acc1[r] + bp1[r*E + ct*16];
        y1 = (y1 >= 0.f) ? y1 : NEG * y1;
        s0[r] += y0 * wl;
        s1[r] += y1 * wl;
      }
    }

    // reduce over n (16 lanes = l within ct, accumulated across ct), logits -> LDS
    #pragma unroll
    for (int r = 0; r < 4; r++){
      float a = s0[r], c = s1[r];
      a += __shfl_xor(a, 1, 64); c += __shfl_xor(c, 1, 64);
      a += __shfl_xor(a, 2, 64); c += __shfl_xor(c, 2, 64);
      a += __shfl_xor(a, 4, 64); c += __shfl_xor(c, 4, 64);
      a += __shfl_xor(a, 8, 64); c += __shfl_xor(c, 8, 64);
      if (n == 0){
        int m0 = rw + q*4 + r;
        float lg = u_i + a + ab;
        lg = (lg >= 0.f) ? lg : NEG * lg;
        sLog[j0 + m0] = lg;
        int m1 = m0 + 16;
        float lh = u_i + c + ab;
        lh = (lh >= 0.f) ? lh : NEG * lh;
        sLog[j0 + m1] = lh;
      }
    }
  }

  __syncthreads();

  // mask + softmax over sLog (in place: each thread owns slots 4t..4t+3)
  int lw = t & 63, wv = t >> 6;
  float4 lv = *(const float4*)(&sLog[4*t]);
  int4   av = *(const int4*)  (adj + (size_t)i*N + 4*t);
  float v0 = (av.x == 1) ? lv.x : -__builtin_inff();
  float v1 = (av.y == 1) ? lv.y : -__builtin_inff();
  float v2 = (av.z == 1) ? lv.z : -__builtin_inff();
  float v3 = (av.w == 1) ? lv.w : -__builtin_inff();
  float mymax = fmaxf(fmaxf(v0, v1), fmaxf(v2, v3));
  #pragma unroll
  for (int o = 32; o > 0; o >>= 1) mymax = fmaxf(mymax, __shfl_xor(mymax, o, 64));
  if (lw == 0) wred[wv] = mymax;
  __syncthreads();
  float M = fmaxf(fmaxf(wred[0], wred[1]), fmaxf(wred[2], wred[3]));
  __syncthreads();

  float e0 = __expf(v0 - M), e1 = __expf(v1 - M), e2 = __expf(v2 - M), e3 = __expf(v3 - M);
  *(float4*)(&sLog[4*t]) = (float4){e0, e1, e2, e3};
  float mysum = (e0 + e1) + (e2 + e3);
  #pragma unroll
  for (int o = 32; o > 0; o >>= 1) mysum += __shfl_xor(mysum, o, 64);
  if (lw == 0) wred[wv] = mysum;
  __syncthreads();
  float inv = 1.0f / (wred[0] + wred[1] + wred[2] + wred[3]);

  // nbc = attn @ embs (embs is L2-resident), concat
  int l = t & 127, jh = t >> 7;
  float acc = 0.f;
  #pragma unroll 8
  for (int jj = 0; jj < 512; jj++){
    int j = jh*512 + jj;
    acc += sLog[j] * embs[j*E + l];
  }
  red[t] = acc; __syncthreads();
  if (t < 128){
    out[(size_t)i*2*E + t]     = embs[i*E + t];
    out[(size_t)i*2*E + E + t] = (red[t] + red[t+128]) * inv;
  }
}

extern "C" void kernel_launch(void* const* d_in, const int* in_sizes, int n_in,
                              void* d_out, int out_size, void* d_ws, size_t ws_size,
                              hipStream_t stream) {
  const float* embs = (const float*)d_in[0];
  const int*   adj  = (const int*)d_in[1];
  const float* pde  = (const float*)d_in[2];
  const float* W    = (const float*)d_in[3];
  const float* pc_W = (const float*)d_in[4];
  const float* pc_b = (const float*)d_in[5];
  const float* a_W  = (const float*)d_in[6];
  const float* a_b  = (const float*)d_in[7];
  float* out = (float*)d_out;

  float* ws      = (float*)d_ws;
  // (logits slot retained in layout but unused by the fused kernel)
  float* bias    = ws + (size_t)N*N;            // N*E floats
  float* u       = bias + (size_t)N*E;          // N floats
  float* w2      = u + N;                       // E floats
  short* BT      = (short*)(w2 + E);            // E*E bf16 (16B-aligned offset)

  prep<<<dim3(E + N), dim3(E), 0, stream>>>(embs, W, pc_W, pc_b, a_W, BT, w2, bias, u);
  fused<<<dim3(N), dim3(256), 0, stream>>>(pde, BT, bias, u, w2, a_b, adj, embs, out);
}

// Round 6
// 862.973 us; speedup vs baseline: 1.2974x; 1.2974x over previous
//
#include <hip/hip_runtime.h>
#include <hip/hip_bf16.h>

#define N 1024
#define E 128
#define NEG 0.2f
#define AST 136  // padded LDS stride (shorts) for B tile

typedef __attribute__((ext_vector_type(8))) short short8;
typedef __attribute__((ext_vector_type(4))) float float4v;

__device__ __forceinline__ short f2bf(float x){
  unsigned u = __float_as_uint(x);
  u += 0x7fffu + ((u >> 16) & 1u);   // round-to-nearest-even
  return (short)(u >> 16);
}

__device__ __forceinline__ short8 cvt2v(float4v a, float4v b){
  short8 r;
  r[0] = f2bf(a[0]); r[1] = f2bf(a[1]); r[2] = f2bf(a[2]); r[3] = f2bf(a[3]);
  r[4] = f2bf(b[0]); r[5] = f2bf(b[1]); r[6] = f2bf(b[2]); r[7] = f2bf(b[3]);
  return r;
}

// Merged prep: blocks [0,E) do prep0 (l=b); blocks [E, E+N) do prep1 (j=b-E).
__global__ void prep(const float* __restrict__ embs, const float* __restrict__ W,
                     const float* __restrict__ pc_W, const float* __restrict__ pc_b,
                     const float* __restrict__ a_W,
                     short* __restrict__ BT, float* __restrict__ w2,
                     float* __restrict__ bias, float* __restrict__ u){
  int b = blockIdx.x, t = threadIdx.x;
  __shared__ float se[E], swf[E], red[E];
  if (b < E){
    int l = b;
    BT[l*E + t] = f2bf(pc_W[(E + t)*E + l]);
    red[t] = W[l*E + t] * a_W[E + t];
    __syncthreads();
    for (int s = 64; s > 0; s >>= 1){ if (t < s) red[t] += red[t+s]; __syncthreads(); }
    if (t == 0) w2[l] = red[0];
  } else {
    int j = b - E;
    se[t] = embs[j*E + t];
    __syncthreads();
    float acc = 0.f;
    #pragma unroll 8
    for (int k = 0; k < E; k++) acc += se[k] * W[k*E + t];
    swf[t] = acc;
    __syncthreads();
    float ct = 0.f;
    #pragma unroll 8
    for (int k = 0; k < E; k++) ct += swf[k] * pc_W[k*E + t];
    bias[j*E + t] = ct + pc_b[t];
    red[t] = swf[t] * a_W[t];
    __syncthreads();
    for (int s = 64; s > 0; s >>= 1){ if (t < s) red[t] += red[t+s]; __syncthreads(); }
    if (t == 0) u[j] = red[0];
  }
}

// Fused kernel: one block per output row i. pde[i,:,:] is a CONTIGUOUS 512 KB
// stream (j-tiles of 128 rows are contiguous 64 KB blocks). Computes all 1024
// logits for row i into LDS, then mask+softmax+attn@embs+concat in-block.
// NOTE: no min-waves clamp in launch_bounds — the (256,4) clamp capped VGPRs
// at 64 and spilled ~700 MB/dispatch of scratch (seen as WRITE_SIZE 718 MB).
__global__ __launch_bounds__(256)
void fused(const float* __restrict__ pde, const short* __restrict__ BT,
           const float* __restrict__ bias, const float* __restrict__ u,
           const float* __restrict__ w2, const float* __restrict__ a_b,
           const int* __restrict__ adj, const float* __restrict__ embs,
           float* __restrict__ out){
  __shared__ __align__(16) short sB[E*AST];   // ~34 KB
  __shared__ __align__(16) float sLog[N];     // 4 KB: logits -> exp values
  __shared__ float sW2[E];
  __shared__ float red[256];
  __shared__ float wred[4];

  const int t = threadIdx.x;
  const int i = blockIdx.x;

  // stage B (bf16, 128x128) into padded LDS
  {
    int rl = t >> 4;
    int kk = (t & 15) * 8;
    #pragma unroll
    for (int p = 0; p < 8; p++){
      int l = p*16 + rl;
      *(uint4*)(&sB[l*AST + kk]) = *(const uint4*)(&BT[l*E + kk]);
    }
  }
  if (t < 128) sW2[t] = w2[t];

  const int lane = t & 63;
  const int w = t >> 6;            // wave 0..3, j-rows [w*32, w*32+32) within tile
  const int n = lane & 15;
  const int q = lane >> 4;
  const int rw = w * 32;

  const float u_i = u[i];
  const float ab = a_b[0];

  __syncthreads();

  const float* pbase = pde + (size_t)i * N * E;

  #pragma unroll 1
  for (int jt = 0; jt < 8; jt++){
    const int j0 = jt * 128;

    // A fragments: direct global->reg from a contiguous 64 KB j-tile.
    // A[row=n][k=q*8+jj], rows are j-rows (stride E floats, contiguous).
    const float* rp0 = pbase + (size_t)(j0 + rw + n) * E + q*8;
    const float* rp1 = rp0 + 16 * E;

    short8 frag[2][4];
    #pragma unroll
    for (int ks = 0; ks < 4; ks++){
      float4v a0 = __builtin_nontemporal_load((const float4v*)(rp0 + ks*32));
      float4v a1 = __builtin_nontemporal_load((const float4v*)(rp0 + ks*32 + 4));
      float4v b0 = __builtin_nontemporal_load((const float4v*)(rp1 + ks*32));
      float4v b1 = __builtin_nontemporal_load((const float4v*)(rp1 + ks*32 + 4));
      frag[0][ks] = cvt2v(a0, a1);
      frag[1][ks] = cvt2v(b0, b1);
    }

    // bias varies with the row (j) axis: per-lane L2 loads.
    // lane needs bias[j0 + rw + q*4 + r (+16)][ct*16 + n]
    const float* bp0 = bias + (size_t)(j0 + rw + q*4) * E + n;
    const float* bp1 = bp0 + 16 * E;

    float s0[4] = {0.f, 0.f, 0.f, 0.f};   // partial logit sums, rows rw+q*4+r
    float s1[4] = {0.f, 0.f, 0.f, 0.f};   // rows +16

    #pragma unroll
    for (int ct = 0; ct < 8; ct++){
      const int l = ct*16 + n;
      short8 b[4];
      #pragma unroll
      for (int ks = 0; ks < 4; ks++)
        b[ks] = *(const short8*)(&sB[l*AST + ks*32 + q*8]);

      float4v acc0 = (float4v){0.f,0.f,0.f,0.f};
      float4v acc1 = (float4v){0.f,0.f,0.f,0.f};
      #pragma unroll
      for (int ks = 0; ks < 4; ks++){
        acc0 = __builtin_amdgcn_mfma_f32_16x16x32_bf16(frag[0][ks], b[ks], acc0, 0, 0, 0);
        acc1 = __builtin_amdgcn_mfma_f32_16x16x32_bf16(frag[1][ks], b[ks], acc1, 0, 0, 0);
      }

      const float wl = sW2[l];
      #pragma unroll
      for (int r = 0; r < 4; r++){
        float y0 = acc0[r] + bp0[r*E + ct*16];
        y0 = (y0 >= 0.f) ? y0 : NEG * y0;
        float y1 = acc1[r] + bp1[r*E + ct*16];
        y1 = (y1 >= 0.f) ? y1 : NEG * y1;
        s0[r] += y0 * wl;
        s1[r] += y1 * wl;
      }
    }

    // reduce over n (16 lanes = l within ct, accumulated across ct), logits -> LDS
    #pragma unroll
    for (int r = 0; r < 4; r++){
      float a = s0[r], c = s1[r];
      a += __shfl_xor(a, 1, 64); c += __shfl_xor(c, 1, 64);
      a += __shfl_xor(a, 2, 64); c += __shfl_xor(c, 2, 64);
      a += __shfl_xor(a, 4, 64); c += __shfl_xor(c, 4, 64);
      a += __shfl_xor(a, 8, 64); c += __shfl_xor(c, 8, 64);
      if (n == 0){
        int m0 = rw + q*4 + r;
        float lg = u_i + a + ab;
        lg = (lg >= 0.f) ? lg : NEG * lg;
        sLog[j0 + m0] = lg;
        int m1 = m0 + 16;
        float lh = u_i + c + ab;
        lh = (lh >= 0.f) ? lh : NEG * lh;
        sLog[j0 + m1] = lh;
      }
    }
  }

  __syncthreads();

  // mask + softmax over sLog (in place: each thread owns slots 4t..4t+3)
  int lw = t & 63, wv = t >> 6;
  float4 lv = *(const float4*)(&sLog[4*t]);
  int4   av = *(const int4*)  (adj + (size_t)i*N + 4*t);
  float v0 = (av.x == 1) ? lv.x : -__builtin_inff();
  float v1 = (av.y == 1) ? lv.y : -__builtin_inff();
  float v2 = (av.z == 1) ? lv.z : -__builtin_inff();
  float v3 = (av.w == 1) ? lv.w : -__builtin_inff();
  float mymax = fmaxf(fmaxf(v0, v1), fmaxf(v2, v3));
  #pragma unroll
  for (int o = 32; o > 0; o >>= 1) mymax = fmaxf(mymax, __shfl_xor(mymax, o, 64));
  if (lw == 0) wred[wv] = mymax;
  __syncthreads();
  float M = fmaxf(fmaxf(wred[0], wred[1]), fmaxf(wred[2], wred[3]));
  __syncthreads();

  float e0 = __expf(v0 - M), e1 = __expf(v1 - M), e2 = __expf(v2 - M), e3 = __expf(v3 - M);
  *(float4*)(&sLog[4*t]) = (float4){e0, e1, e2, e3};
  float mysum = (e0 + e1) + (e2 + e3);
  #pragma unroll
  for (int o = 32; o > 0; o >>= 1) mysum += __shfl_xor(mysum, o, 64);
  if (lw == 0) wred[wv] = mysum;
  __syncthreads();
  float inv = 1.0f / (wred[0] + wred[1] + wred[2] + wred[3]);

  // nbc = attn @ embs (embs is L2-resident), concat
  int l = t & 127, jh = t >> 7;
  float acc = 0.f;
  #pragma unroll 8
  for (int jj = 0; jj < 512; jj++){
    int j = jh*512 + jj;
    acc += sLog[j] * embs[j*E + l];
  }
  red[t] = acc; __syncthreads();
  if (t < 128){
    out[(size_t)i*2*E + t]     = embs[i*E + t];
    out[(size_t)i*2*E + E + t] = (red[t] + red[t+128]) * inv;
  }
}

extern "C" void kernel_launch(void* const* d_in, const int* in_sizes, int n_in,
                              void* d_out, int out_size, void* d_ws, size_t ws_size,
                              hipStream_t stream) {
  const float* embs = (const float*)d_in[0];
  const int*   adj  = (const int*)d_in[1];
  const float* pde  = (const float*)d_in[2];
  const float* W    = (const float*)d_in[3];
  const float* pc_W = (const float*)d_in[4];
  const float* pc_b = (const float*)d_in[5];
  const float* a_W  = (const float*)d_in[6];
  const float* a_b  = (const float*)d_in[7];
  float* out = (float*)d_out;

  float* ws      = (float*)d_ws;
  // (logits slot retained in layout but unused by the fused kernel)
  float* bias    = ws + (size_t)N*N;            // N*E floats
  float* u       = bias + (size_t)N*E;          // N floats
  float* w2      = u + N;                       // E floats
  short* BT      = (short*)(w2 + E);            // E*E bf16 (16B-aligned offset)

  prep<<<dim3(E + N), dim3(E), 0, stream>>>(embs, W, pc_W, pc_b, a_W, BT, w2, bias, u);
  fused<<<dim3(N), dim3(256), 0, stream>>>(pde, BT, bias, u, w2, a_b, adj, embs, out);
}